// Round 1
// baseline (220.007 us; speedup 1.0000x reference)
//
#include <hip/hip_runtime.h>
#include <math.h>

// Sobel gradient magnitude, zero-padded 3x3 cross stencil.
// x: [8, 64, 256, 256] f32 -> out same shape.
// gv = x[i+1,j] - x[i-1,j]; gh = x[i,j+1] - x[i,j-1]; out = sqrt(gv^2+gh^2+eps)

#define PLANE_H 256
#define PLANE_W 256
#define VECW 64   // PLANE_W / 4

__global__ __launch_bounds__(256) void sobel_kernel(const float* __restrict__ x,
                                                    float* __restrict__ out,
                                                    int total_vec) {
    int idx = blockIdx.x * blockDim.x + threadIdx.x;
    if (idx >= total_vec) return;

    int j4    = idx & (VECW - 1);          // vec-column within row
    int row   = (idx >> 6) & (PLANE_H - 1);
    int plane = idx >> 14;                 // 64 * 256 = 2^14 vecs per plane

    size_t base = ((size_t)plane << 16) + ((size_t)row << 8) + ((size_t)j4 << 2);
    const float* p = x + base;

    float4 c  = *(const float4*)p;
    float4 up = (row > 0)           ? *(const float4*)(p - PLANE_W)
                                    : make_float4(0.f, 0.f, 0.f, 0.f);
    float4 dn = (row < PLANE_H - 1) ? *(const float4*)(p + PLANE_W)
                                    : make_float4(0.f, 0.f, 0.f, 0.f);
    float left  = (j4 > 0)        ? p[-1] : 0.f;
    float right = (j4 < VECW - 1) ? p[4]  : 0.f;

    const float eps = 1e-6f;

    float gh0 = c.y   - left;
    float gh1 = c.z   - c.x;
    float gh2 = c.w   - c.y;
    float gh3 = right - c.z;

    float gv0 = dn.x - up.x;
    float gv1 = dn.y - up.y;
    float gv2 = dn.z - up.z;
    float gv3 = dn.w - up.w;

    float4 o;
    o.x = sqrtf(gv0 * gv0 + gh0 * gh0 + eps);
    o.y = sqrtf(gv1 * gv1 + gh1 * gh1 + eps);
    o.z = sqrtf(gv2 * gv2 + gh2 * gh2 + eps);
    o.w = sqrtf(gv3 * gv3 + gh3 * gh3 + eps);

    *(float4*)(out + base) = o;
}

extern "C" void kernel_launch(void* const* d_in, const int* in_sizes, int n_in,
                              void* d_out, int out_size, void* d_ws, size_t ws_size,
                              hipStream_t stream) {
    const float* x = (const float*)d_in[0];
    float* out = (float*)d_out;
    int total_vec = out_size / 4;          // one thread per float4
    int block = 256;
    int grid = (total_vec + block - 1) / block;
    sobel_kernel<<<grid, block, 0, stream>>>(x, out, total_vec);
}